// Round 1
// 2870.961 us; speedup vs baseline: 1.0407x; 1.0407x over previous
//
#include <hip/hip_runtime.h>

typedef __attribute__((ext_vector_type(8))) short short8;
typedef __attribute__((ext_vector_type(4))) float floatx4;
typedef unsigned int uint;
typedef unsigned short ushort;
typedef unsigned long long ull;
typedef __attribute__((ext_vector_type(4))) uint uintx4;
typedef __attribute__((ext_vector_type(4))) int intx4;

#define B_ 512
#define S_ 200
#define H_ 512
#define VOCAB_ 2002

__device__ __forceinline__ ushort f2bfbits(float f) {
  union { float f; uint u; } c; c.f = f;
  uint u = c.u;
  u += 0x7fffu + ((u >> 16) & 1u);   // RNE
  return (ushort)(u >> 16);
}
__device__ __forceinline__ float bf2f_(ushort u) {
  union { uint i; float f; } c; c.i = ((uint)u) << 16; return c.f;
}
__device__ __forceinline__ float sigmoidf_(float x) { return 1.f / (1.f + __expf(-x)); }
__device__ __forceinline__ float tanhf_(float x) { return 2.f / (1.f + __expf(-2.f * x)) - 1.f; }
__device__ __forceinline__ float clamp30(float x) { return fminf(fmaxf(x, -30.f), 30.f); }

// split f32[8] -> (hi, lo) bf16 short8 pair; hi+lo carries ~16 mantissa bits
__device__ __forceinline__ void split8(const float* p, short8& hi, short8& lo) {
#pragma unroll
  for (int j = 0; j < 8; ++j) {
    const float f = p[j];
    const ushort h = f2bfbits(f);
    hi[j] = (short)h;
    lo[j] = (short)f2bfbits(f - bf2f_(h));
  }
}

// --- coherent (agent-safe, L1/L2-bypassing) 32B load: issue only, no wait ---
__device__ __forceinline__ void ld32_cc(const void* p, uintx4& a, uintx4& b) {
  asm volatile("global_load_dwordx4 %0, %2, off sc0 sc1\n\t"
               "global_load_dwordx4 %1, %2, off offset:16 sc0 sc1"
               : "=&v"(a), "=&v"(b)
               : "v"(p));
}
// --- coherent 32B load with embedded drain (for the spin poll) ---
__device__ __forceinline__ void ld32_cc_wait(const void* p, intx4& a, intx4& b) {
  asm volatile("global_load_dwordx4 %0, %2, off sc0 sc1\n\t"
               "global_load_dwordx4 %1, %2, off offset:16 sc0 sc1\n\t"
               "s_waitcnt vmcnt(0)"
               : "=&v"(a), "=&v"(b)
               : "v"(p)
               : "memory");
}
__device__ __forceinline__ void vm_wait0() {
  asm volatile("s_waitcnt vmcnt(0)" ::: "memory");
}

// ---------------------------------------------------------------------------
// K1: EncGates[v][n] = emb[v]·W_ih[n]  (f32-accurate via 3-product split MFMA)
// grid (32,126) x 256 thr (4 waves, one 16x16 tile each). Biases added later.
// ---------------------------------------------------------------------------
template <typename ET>
__global__ void encg_kernel(const float* __restrict__ emb, const float* __restrict__ Wih,
                            ET* __restrict__ encg) {
  const int w = threadIdx.x >> 6, l = threadIdx.x & 63;
  const int ln = l & 15, lk = l >> 4;
  const int n = (blockIdx.x * 4 + w) * 16 + ln;
  const int m = blockIdx.y * 16 + ln;
  const int mA = (m < VOCAB_) ? m : 0;
  const float* ap = emb + (size_t)mA * 512 + lk * 8;
  const float* bp = Wih + (size_t)n * 512 + lk * 8;
  floatx4 acc = {0.f, 0.f, 0.f, 0.f};
#pragma unroll 4
  for (int kk = 0; kk < 16; ++kk) {
    short8 ah, al, bh, bl;
    split8(ap + kk * 32, ah, al);
    split8(bp + kk * 32, bh, bl);
    acc = __builtin_amdgcn_mfma_f32_16x16x32_bf16(ah, bh, acc, 0, 0, 0);
    acc = __builtin_amdgcn_mfma_f32_16x16x32_bf16(ah, bl, acc, 0, 0, 0);
    acc = __builtin_amdgcn_mfma_f32_16x16x32_bf16(al, bh, acc, 0, 0, 0);
  }
#pragma unroll
  for (int r = 0; r < 4; ++r) {
    const int mo = blockIdx.y * 16 + lk * 4 + r;   // C/D: row=(lane>>4)*4+reg
    if (mo < VOCAB_) {
      if constexpr (sizeof(ET) == 2)
        encg[(size_t)mo * 2048 + n] = (ET)f2bfbits(acc[r]);
      else
        encg[(size_t)mo * 2048 + n] = acc[r];       // col = lane&15
    }
  }
}

// ---------------------------------------------------------------------------
// K2: et[s][b] = sigmoid(P[u].Q[k] + Pb[u] + Qb[k]); f32. grid (200,128)x256.
// ---------------------------------------------------------------------------
__global__ void mf_kernel(const int* __restrict__ us, const int* __restrict__ ss,
                          const float* __restrict__ P, const float* __restrict__ Q,
                          const float* __restrict__ Pb, const float* __restrict__ Qb,
                          float* __restrict__ etb) {
  const int s = blockIdx.x;
  const int w = threadIdx.x >> 6, l = threadIdx.x & 63;
  const int b = blockIdx.y * 4 + w;
  const int u = us[b * S_ + s];
  const int k = ss[b * S_ + s];
  const float4 p0 = *(const float4*)(P + (size_t)u * 512 + l * 8);
  const float4 p1 = *(const float4*)(P + (size_t)u * 512 + l * 8 + 4);
  const float4 q0 = *(const float4*)(Q + (size_t)k * 512 + l * 8);
  const float4 q1 = *(const float4*)(Q + (size_t)k * 512 + l * 8 + 4);
  float dot = p0.x*q0.x + p0.y*q0.y + p0.z*q0.z + p0.w*q0.w
            + p1.x*q1.x + p1.y*q1.y + p1.z*q1.z + p1.w*q1.w;
#pragma unroll
  for (int off = 32; off > 0; off >>= 1) dot += __shfl_xor(dot, off);
  if (l == 0)
    etb[s * B_ + b] = sigmoidf_(dot + Pb[u] + Qb[k]);
}

// ---------------------------------------------------------------------------
// K3: recurrent LSTM, f32-accurate. 256 blocks x 512 thr, 1 block/CU.
// group g=bid&15 owns 32 batch rows; slice ns=bid>>4 owns 32 h-units.
//
// r9 changes vs r8:
//  - Ah/Al LDS: unpadded [32][512] with XOR swizzle (col ^ ((row&7)<<3)) ->
//    ds_read_b128/ds_write_b128 uniform 8 dw/bank, conflict-free (was 528-pad,
//    264 dw stride == 8 mod 32 -> 4-8-way conflicts, 2.0e8 conflict cycles).
//  - staging: 2x16B asm global_load_dwordx4 sc0 sc1 per array per half (was
//    16x8B atomic loads); half-1 loads ISSUED before half-0 MFMAs (T14 split)
//    so one MALL round trip hides under 48 MFMAs.
//  - per-WAVE slot publish after per-wave vmcnt(0) drain (8 slots/block in one
//    64B line) removes the end-of-step __syncthreads from the critical path.
//    Consumer poll: lane p reads producer p's 8 wave-slots as 2x dwordx4 in a
//    single round trip. Visibility argument unchanged from r8 (data stores
//    drained to coherence point before slot store issues; MALL serializes).
//  - gp_lds pad 36->37 floats (odd stride -> <=2-way, free), scalar stores.
// ---------------------------------------------------------------------------
template <typename ET>
__global__ __launch_bounds__(512, 2) void lstm_kernel(
    const int* __restrict__ tok, const ET* __restrict__ encg,
    const float* __restrict__ etb, const float* __restrict__ Whh,
    const float* __restrict__ bih, const float* __restrict__ bhh,
    ushort* ht_hi, ushort* ht_lo, int* ctr) {
  __shared__ __align__(16) ushort Ah_lds[32 * 512];   // 32,768 B (XOR-swizzled)
  __shared__ __align__(16) ushort Al_lds[32 * 512];   // 32,768 B
  __shared__ float gp_lds[128 * 37];                  // 18,944 B

  const int bid = blockIdx.x;
  const int g = bid & 15, ns = bid >> 4;
  const int b0 = g * 32, h0 = ns * 32;
  const int tid = threadIdx.x;
  const int w = tid >> 6, l = tid & 63;
  const int ln = l & 15, lk = l >> 4;
  const int q = w >> 1;                 // gate (i,f,g,o)
  const int c0w = (w & 1) * 16;         // col sub-tile within 32 h-units

  // slots: group g's producer block ns publishes 8 wave-slots at
  // ctr[g*256 + ns*16 .. +8) -- one 64-B line per block.
  int* const myslot = ctr + g * 256 + ns * 16;
  const int* const gslots = ctr + g * 256;

  // --- preload + split this wave's W_hh rows (16 gate cols), once ---
  short8 Bh[16], Bl[16];
  {
    const float* wr = Whh + (size_t)(q * 512 + h0 + c0w + ln) * 512 + lk * 8;
#pragma unroll 4
    for (int kk = 0; kk < 16; ++kk)
      split8(wr + kk * 32, Bh[kk], Bl[kk]);
  }

  const int sr = tid >> 4;              // batch row within group (0..31)
  const int sc = tid & 15;              // 16 stagers per row
  const int hh = sc * 2;
  const int bg = b0 + sr;
  float ct0 = 0.f, ct1 = 0.f;

  float bs[4][2];
#pragma unroll
  for (int qq = 0; qq < 4; ++qq) {
    const int col = qq * 512 + h0 + hh;
    bs[qq][0] = bih[col] + bhh[col];
    bs[qq][1] = bih[col + 1] + bhh[col + 1];
  }

  const int swzw = (sr & 7) << 3;       // writer swizzle (ushort units)
  const int swzr = (ln & 7) << 3;       // reader swizzle (row&7 == ln&7 for both mt)

  for (int s = 0; s < S_; ++s) {
    // ---- prefetch nonlinearity inputs (ht-independent; hides under spin) ----
    const int tv = tok[bg * S_ + s];
    float ev = etb[s * B_ + bg];
    float ex[4], ey[4];
#pragma unroll
    for (int qq = 0; qq < 4; ++qq) {
      if constexpr (sizeof(ET) == 2) {
        const uint e2 = *(const uint*)((const ushort*)encg + (size_t)tv * 2048 + qq * 512 + h0 + hh);
        ex[qq] = bf2f_((ushort)(e2 & 0xffffu)); ey[qq] = bf2f_((ushort)(e2 >> 16));
      } else {
        const float2 e = *(const float2*)((const float*)encg + (size_t)tv * 2048 + qq * 512 + h0 + hh);
        ex[qq] = e.x; ey[qq] = e.y;
      }
    }

    // ---- wait for all 16 producers (8 wave-slots each) to reach step s ----
    if (s > 0 && tid < 16) {
      const int* sp = gslots + tid * 16;
      for (;;) {
        intx4 va, vb;
        ld32_cc_wait(sp, va, vb);
        if (va[0] >= s && va[1] >= s && va[2] >= s && va[3] >= s &&
            vb[0] >= s && vb[1] >= s && vb[2] >= s && vb[3] >= s) break;
      }
    }
    __syncthreads();                                     // bar A

    const size_t rdo = (size_t)(s & 1) * (B_ * H_);
    const size_t wro = (size_t)((s & 1) ^ 1) * (B_ * H_);
    const ushort* hrow = ht_hi + rdo + (size_t)bg * 512;
    const ushort* lrow = ht_lo + rdo + (size_t)bg * 512;

    // ---- stage half 0 (cols 0..255): 2x32B coherent loads -> swizzled LDS ----
    {
      const int c = sc * 16;
      uintx4 ah0, ah1, al0, al1;
      ld32_cc(hrow + c, ah0, ah1);
      ld32_cc(lrow + c, al0, al1);
      vm_wait0();
      const int d0 = sr * 512 + (c ^ swzw);
      const int d1 = sr * 512 + ((c + 8) ^ swzw);
      *(uintx4*)(Ah_lds + d0) = ah0; *(uintx4*)(Ah_lds + d1) = ah1;
      *(uintx4*)(Al_lds + d0) = al0; *(uintx4*)(Al_lds + d1) = al1;
    }
    __syncthreads();                                     // bar B

    // ---- issue half-1 loads NOW; they complete under half-0's MFMAs ----
    const int c1 = 256 + sc * 16;
    uintx4 nh0, nh1, nl0, nl1;
    ld32_cc(hrow + c1, nh0, nh1);
    ld32_cc(lrow + c1, nl0, nl1);

    // ---- MFMA half 0 (kk 0..7) ----
    floatx4 acc0 = {0.f, 0.f, 0.f, 0.f};
    floatx4 acc1 = {0.f, 0.f, 0.f, 0.f};
#pragma unroll
    for (int kk = 0; kk < 8; ++kk) {
      const int csw = (kk * 32 + lk * 8) ^ swzr;
      {
        const int ao = ln * 512 + csw;
        const short8 ah = *(const short8*)(Ah_lds + ao);
        const short8 al = *(const short8*)(Al_lds + ao);
        acc0 = __builtin_amdgcn_mfma_f32_16x16x32_bf16(ah, Bh[kk], acc0, 0, 0, 0);
        acc0 = __builtin_amdgcn_mfma_f32_16x16x32_bf16(ah, Bl[kk], acc0, 0, 0, 0);
        acc0 = __builtin_amdgcn_mfma_f32_16x16x32_bf16(al, Bh[kk], acc0, 0, 0, 0);
      }
      {
        const int ao = (16 + ln) * 512 + csw;
        const short8 ah = *(const short8*)(Ah_lds + ao);
        const short8 al = *(const short8*)(Al_lds + ao);
        acc1 = __builtin_amdgcn_mfma_f32_16x16x32_bf16(ah, Bh[kk], acc1, 0, 0, 0);
        acc1 = __builtin_amdgcn_mfma_f32_16x16x32_bf16(ah, Bl[kk], acc1, 0, 0, 0);
        acc1 = __builtin_amdgcn_mfma_f32_16x16x32_bf16(al, Bh[kk], acc1, 0, 0, 0);
      }
    }

    // ---- drain half-1 loads, write to LDS ----
    vm_wait0();
    __builtin_amdgcn_sched_barrier(0);
    {
      const int d0 = sr * 512 + (c1 ^ swzw);
      const int d1 = sr * 512 + ((c1 + 8) ^ swzw);
      *(uintx4*)(Ah_lds + d0) = nh0; *(uintx4*)(Ah_lds + d1) = nh1;
      *(uintx4*)(Al_lds + d0) = nl0; *(uintx4*)(Al_lds + d1) = nl1;
    }
    __syncthreads();                                     // bar C

    // ---- MFMA half 1 (kk 8..15) ----
#pragma unroll
    for (int kk = 8; kk < 16; ++kk) {
      const int csw = (kk * 32 + lk * 8) ^ swzr;
      {
        const int ao = ln * 512 + csw;
        const short8 ah = *(const short8*)(Ah_lds + ao);
        const short8 al = *(const short8*)(Al_lds + ao);
        acc0 = __builtin_amdgcn_mfma_f32_16x16x32_bf16(ah, Bh[kk], acc0, 0, 0, 0);
        acc0 = __builtin_amdgcn_mfma_f32_16x16x32_bf16(ah, Bl[kk], acc0, 0, 0, 0);
        acc0 = __builtin_amdgcn_mfma_f32_16x16x32_bf16(al, Bh[kk], acc0, 0, 0, 0);
      }
      {
        const int ao = (16 + ln) * 512 + csw;
        const short8 ah = *(const short8*)(Ah_lds + ao);
        const short8 al = *(const short8*)(Al_lds + ao);
        acc1 = __builtin_amdgcn_mfma_f32_16x16x32_bf16(ah, Bh[kk], acc1, 0, 0, 0);
        acc1 = __builtin_amdgcn_mfma_f32_16x16x32_bf16(ah, Bl[kk], acc1, 0, 0, 0);
        acc1 = __builtin_amdgcn_mfma_f32_16x16x32_bf16(al, Bh[kk], acc1, 0, 0, 0);
      }
    }

    // ---- gate-partials -> LDS (row = block gate-col q*32+hcol, col = brow) ----
    {
      const int gb = (w * 16 + ln) * 37;
#pragma unroll
      for (int r = 0; r < 4; ++r) {
        gp_lds[gb + lk * 4 + r] = acc0[r];
        gp_lds[gb + 16 + lk * 4 + r] = acc1[r];
      }
    }
    __syncthreads();                                     // bar D

    // ---- nonlinearity: thread owns (row sr, h-units hh, hh+1) ----
    {
      ev = fminf(fmaxf(ev, 0.f), 1.f);
      float Gv[4][2];
#pragma unroll
      for (int qq = 0; qq < 4; ++qq) {
        Gv[qq][0] = clamp30(gp_lds[(qq * 32 + hh) * 37 + sr] + ex[qq] + bs[qq][0]);
        Gv[qq][1] = clamp30(gp_lds[(qq * 32 + hh + 1) * 37 + sr] + ey[qq] + bs[qq][1]);
      }
      const float scale = 1.f + ev;
      float c0v = ct0 * scale;
      c0v = sigmoidf_(Gv[1][0]) * c0v + sigmoidf_(Gv[0][0]) * tanhf_(Gv[2][0]);
      const float h0v = sigmoidf_(Gv[3][0]) * tanhf_(c0v);
      ct0 = c0v;                                   // UNCLAMPED (ref semantics)
      float c1v = ct1 * scale;
      c1v = sigmoidf_(Gv[1][1]) * c1v + sigmoidf_(Gv[0][1]) * tanhf_(Gv[2][1]);
      const float h1v = sigmoidf_(Gv[3][1]) * tanhf_(c1v);
      ct1 = c1v;
      const ushort h0h = f2bfbits(h0v), h1h = f2bfbits(h1v);
      const ushort h0l = f2bfbits(h0v - bf2f_(h0h)), h1l = f2bfbits(h1v - bf2f_(h1h));
      const size_t wo = wro + (size_t)bg * 512 + h0 + hh;
      __hip_atomic_store((uint*)(ht_hi + wo), (uint)h0h | ((uint)h1h << 16),
                         __ATOMIC_RELAXED, __HIP_MEMORY_SCOPE_AGENT);
      __hip_atomic_store((uint*)(ht_lo + wo), (uint)h0l | ((uint)h1l << 16),
                         __ATOMIC_RELAXED, __HIP_MEMORY_SCOPE_AGENT);
    }

    // ---- per-wave publish: drain THIS wave's ht stores, then set wave-slot.
    // Consumers require all 8 wave-slots of all 16 producers >= s+1, and each
    // slot is stored only after its wave's stores reached the coherence point.
    vm_wait0();
    if (l == 0)
      __hip_atomic_store(myslot + w, s + 1, __ATOMIC_RELAXED, __HIP_MEMORY_SCOPE_AGENT);
  }
}

// ---------------------------------------------------------------------------
// K4: out[b] = sigmoid( (ht_hi+ht_lo)[b] . dec_W[tgt[b]] + dec_b[tgt[b]] )
// grid 128 x 256 (one wave per batch row). Final ht is in buffer parity 0.
// ---------------------------------------------------------------------------
__global__ void dec_kernel(const ushort* __restrict__ hthi, const ushort* __restrict__ htlo,
                           const float* __restrict__ decW, const float* __restrict__ decb,
                           const int* __restrict__ tgt, float* __restrict__ out) {
  const int w = threadIdx.x >> 6, l = threadIdx.x & 63;
  const int b = blockIdx.x * 4 + w;
  const int t = tgt[b];
  const uint4 hv = *(const uint4*)(hthi + (size_t)b * 512 + l * 8);
  const uint4 lv = *(const uint4*)(htlo + (size_t)b * 512 + l * 8);
  const float4 w0 = *(const float4*)(decW + (size_t)t * 512 + l * 8);
  const float4 w1 = *(const float4*)(decW + (size_t)t * 512 + l * 8 + 4);
  const uint ha[4] = {hv.x, hv.y, hv.z, hv.w};
  const uint la[4] = {lv.x, lv.y, lv.z, lv.w};
  float hf[8];
#pragma unroll
  for (int i = 0; i < 4; ++i) {
    hf[2*i]   = bf2f_((ushort)(ha[i] & 0xffffu)) + bf2f_((ushort)(la[i] & 0xffffu));
    hf[2*i+1] = bf2f_((ushort)(ha[i] >> 16))     + bf2f_((ushort)(la[i] >> 16));
  }
  float dot = hf[0]*w0.x + hf[1]*w0.y + hf[2]*w0.z + hf[3]*w0.w
            + hf[4]*w1.x + hf[5]*w1.y + hf[6]*w1.z + hf[7]*w1.w;
#pragma unroll
  for (int off = 32; off > 0; off >>= 1) dot += __shfl_xor(dot, off);
  if (l == 0) out[b] = sigmoidf_(dot + decb[t]);
}

extern "C" void kernel_launch(void* const* d_in, const int* in_sizes, int n_in,
                              void* d_out, int out_size, void* d_ws, size_t ws_size,
                              hipStream_t stream) {
  (void)in_sizes; (void)n_in; (void)out_size;
  const int* main_input = (const int*)d_in[0];
  const int* target_id  = (const int*)d_in[1];
  const int* user_seq   = (const int*)d_in[2];
  const int* skill_seq  = (const int*)d_in[3];
  const float* enc_emb  = (const float*)d_in[4];
  const float* P        = (const float*)d_in[5];
  const float* Q        = (const float*)d_in[6];
  const float* Pb       = (const float*)d_in[7];
  const float* Qb       = (const float*)d_in[8];
  const float* W_ih     = (const float*)d_in[9];
  const float* W_hh     = (const float*)d_in[10];
  const float* b_ih     = (const float*)d_in[11];
  const float* b_hh     = (const float*)d_in[12];
  const float* dec_W    = (const float*)d_in[13];
  const float* dec_b    = (const float*)d_in[14];
  float* out = (float*)d_out;

  // workspace layout (unchanged from r8):
  //   [0)          ht_hi  2*512*512 bf16 = 1,048,576
  //   [1,048,576)  ht_lo  1,048,576                  -> 2,097,152
  //   [2,097,152)  ctr    256 slots x 64 B = 16,384  -> 2,113,536
  //   [2,113,536)  etb    200*512 f32 = 409,600      -> 2,523,136
  //   [2,523,136)  encg   f32 16,400,384 (else bf16 8,200,192)
  char* wsb = (char*)d_ws;
  ushort* ht_hi = (ushort*)wsb;
  ushort* ht_lo = (ushort*)(wsb + 1048576);
  int* ctr = (int*)(wsb + 2097152);
  float* etb = (float*)(wsb + 2113536);
  char* encb = wsb + 2523136;
  const bool enc32 = ws_size >= (size_t)2523136 + 16400384;

  hipMemsetAsync(wsb, 0, 2113536, stream);   // ht(0)=0, all slots=0

  if (enc32)
    encg_kernel<float><<<dim3(32, 126), dim3(256), 0, stream>>>(enc_emb, W_ih, (float*)encb);
  else
    encg_kernel<ushort><<<dim3(32, 126), dim3(256), 0, stream>>>(enc_emb, W_ih, (ushort*)encb);
  mf_kernel<<<dim3(200, 128), dim3(256), 0, stream>>>(user_seq, skill_seq, P, Q, Pb, Qb, etb);
  if (enc32)
    lstm_kernel<float><<<dim3(256), dim3(512), 0, stream>>>(
        main_input, (const float*)encb, etb, W_hh, b_ih, b_hh, ht_hi, ht_lo, ctr);
  else
    lstm_kernel<ushort><<<dim3(256), dim3(512), 0, stream>>>(
        main_input, (const ushort*)encb, etb, W_hh, b_ih, b_hh, ht_hi, ht_lo, ctr);
  dec_kernel<<<dim3(128), dim3(256), 0, stream>>>(ht_hi, ht_lo, dec_W, dec_b, target_id, out);
}